// Round 7
// baseline (396.342 us; speedup 1.0000x reference)
//
#include <hip/hip_runtime.h>

// LightshiftaddLayer — R11: revert to split (R10 fusion was net-negative:
// HBM 208->297 MB, FETCH +32MB from b-major X tiling, fp32 Out doubled
// write bytes; the Y round-trip it removed was L3-absorbed anyway).
//  gemm_bt: exact R7 kernel (96.3us, 0 conflicts, Occ 37%) with
//    launch_bounds (256,4)->(256,5): VGPR 60 and 32KB LDS allow exactly
//    5 blocks/CU (5x32KB = 160KiB); R5->R7 showed time tracks resident
//    blocks in this regime.
//  lconv: 2 t's per thread (8 loads/2 outputs, shares 6 of 8 window taps);
//    L2-side read traffic 470->269 MB, half the waves, v[8] = 32 VGPR only
//    (avoids R8's CHT=8 register wall).
constexpr int T_DIM = 4096;
constexpr int B_DIM = 16;
constexpr int C_DIM = 512;
constexpr int K_CONV = 7;
constexpr int M_DIM = T_DIM * B_DIM;   // 65536 GEMM rows
constexpr int BC = B_DIM * C_DIM;      // 8192

typedef __attribute__((ext_vector_type(8))) short bf16x8;
typedef __attribute__((ext_vector_type(4))) float f32x4;
typedef __attribute__((ext_vector_type(8))) float f32x8;
typedef __attribute__((ext_vector_type(4))) unsigned int u32x4;

__device__ __forceinline__ unsigned short f2bf(float f) {
  unsigned u = __float_as_uint(f);
  u += 0x7fffu + ((u >> 16) & 1u);   // RNE
  return (unsigned short)(u >> 16);
}
__device__ __forceinline__ unsigned pack2(float a, float b) {
  return (unsigned)f2bf(a) | (((unsigned)f2bf(b)) << 16);
}

// ---------------------------------------------------------------- quantize W -> bf16
__global__ __launch_bounds__(256) void quantize_w(
    const float* __restrict__ W, unsigned short* __restrict__ Wq) {
  int i = blockIdx.x * 256 + threadIdx.x;
  float w = W[i];
  float a = fabsf(w) + 1e-12f;
  float q = exp2f(rintf(log2f(a)));       // rintf = RNE, matches jnp.round
  q = (w > 0.f) ? q : ((w < 0.f) ? -q : 0.f);
  Wq[i] = f2bf(q);                        // powers of two: exact in bf16
}

// ---------------------------------------------------------------- GEMM (B^T)
// Y[m,n] = sum_k X[m,k]*Bt[n,k] + bias[n]; X fp32 cast in-flight, Bt bf16.
constexpr int BK = 32;
constexpr int NSTEP = C_DIM / BK;   // 16 K-steps

__global__ __launch_bounds__(256, 5) void gemm_bt(
    const float* __restrict__ X, const short* __restrict__ Bt,
    const float* __restrict__ bias, unsigned short* __restrict__ Y) {
  constexpr int K = C_DIM, N = C_DIM;
  // 128 rows x 32 k bf16 = 64 B/row, 8 KB/tile; dbuf A+B = 32 KB -> 5 blk/CU.
  __shared__ __align__(16) short As[2][128 * BK];
  __shared__ __align__(16) short Bs[2][128 * BK];

  // XCD swizzle: the 4 n-blocks sharing an X m-tile run consecutively on one XCD.
  const int id   = blockIdx.x;            // 0..2047
  const int xcd  = id & 7;
  const int slot = id >> 3;               // 0..255
  const int nb   = slot & 3;
  const int mb   = xcd * 64 + (slot >> 2);
  const int m0 = mb * 128;
  const int n0 = nb * 128;

  const int t    = threadIdx.x;
  const int lane = t & 63;
  const int wid  = t >> 6;               // 4 waves: 2x2 of 64x64

  // ---- A staging: thread t stages rows t>>2 and 64+(t>>2), float col (t&3)*8.
  const int ar = t >> 2;                 // 0..63
  const float* pA = X + (long)(m0 + ar) * K + (t & 3) * 8;
  // swizzled 16B-chunk within 64B row: chunk ^= (row>>1)&3 (same for row+64)
  const int awoff = (((t & 3) ^ ((ar >> 1) & 3)) << 4);

  // ---- B staging via global_load_lds: linear LDS dest (wave base + lane*16),
  // source pre-swizzled: logical chunk = (t&3) ^ ((t>>3)&3).
  const int bc = ((t & 3) ^ ((t >> 3) & 3)) * 8;   // shorts
  const short* pB = Bt + (long)(n0 + (t >> 2)) * K + bc;

  // ---- fragment geometry (A frag: A[m=lane&15][k=(lane>>4)*8+j])
  const int fr = lane & 15;
  const int fq = lane >> 4;
  const int wm = (wid >> 1) * 64;
  const int wn = (wid & 1) * 64;
  // frag row = wm|wn + i*16 + fr -> (row>>1)&3 = (fr>>1)&3 (wave-constant)
  const int sw = ((fq ^ ((fr >> 1) & 3)) << 4);

  f32x4 ax[4];
  f32x4 acc[4][4] = {};

  auto loadA = [&](int k0) {
    ax[0] = *(const f32x4*)(pA + k0);
    ax[1] = *(const f32x4*)(pA + k0 + 4);
    ax[2] = *(const f32x4*)(pA + (long)64 * K + k0);
    ax[3] = *(const f32x4*)(pA + (long)64 * K + k0 + 4);
  };
  auto stageB = [&](int bsel, int k0) {
#pragma unroll
    for (int i = 0; i < 2; ++i)
      __builtin_amdgcn_global_load_lds(
          (const __attribute__((address_space(1))) void*)(pB + (long)i * 64 * K + k0),
          (__attribute__((address_space(3))) void*)&Bs[bsel][i * 2048 + wid * 512],
          16, 0, 0);
  };
  auto writeA = [&](int bsel) {
    char* base = (char*)&As[bsel][0];
    u32x4 w0, w1;
    w0[0] = pack2(ax[0][0], ax[0][1]);
    w0[1] = pack2(ax[0][2], ax[0][3]);
    w0[2] = pack2(ax[1][0], ax[1][1]);
    w0[3] = pack2(ax[1][2], ax[1][3]);
    w1[0] = pack2(ax[2][0], ax[2][1]);
    w1[1] = pack2(ax[2][2], ax[2][3]);
    w1[2] = pack2(ax[3][0], ax[3][1]);
    w1[3] = pack2(ax[3][2], ax[3][3]);
    *(u32x4*)(base + ar * 64 + awoff)        = w0;
    *(u32x4*)(base + (64 + ar) * 64 + awoff) = w1;
  };
  auto compute = [&](int bsel) {
    const char* ab = (const char*)&As[bsel][0];
    const char* bb = (const char*)&Bs[bsel][0];
    bf16x8 af[4], bfr[4];
#pragma unroll
    for (int i = 0; i < 4; ++i)
      af[i] = *(const bf16x8*)(ab + (wm + i * 16 + fr) * 64 + sw);
#pragma unroll
    for (int j = 0; j < 4; ++j)
      bfr[j] = *(const bf16x8*)(bb + (wn + j * 16 + fr) * 64 + sw);
#pragma unroll
    for (int i = 0; i < 4; ++i)
#pragma unroll
      for (int j = 0; j < 4; ++j)
        acc[i][j] = __builtin_amdgcn_mfma_f32_16x16x32_bf16(af[i], bfr[j], acc[i][j], 0, 0, 0);
  };

  // prologue: stage tile 0
  loadA(0);
  stageB(0, 0);
  writeA(0);
  __syncthreads();

  // main loop: ONE barrier per step; s+1 loads in flight across compute(s)
#pragma unroll
  for (int s = 0; s < NSTEP; ++s) {
    const int buf = s & 1;
    if (s + 1 < NSTEP) {
      loadA((s + 1) * BK);
      stageB(buf ^ 1, (s + 1) * BK);
    }
    compute(buf);
    if (s + 1 < NSTEP) {
      writeA(buf ^ 1);
      __syncthreads();
    }
  }

  // epilogue: C/D layout col=lane&15, row=(lane>>4)*4+reg
#pragma unroll
  for (int j = 0; j < 4; ++j) {
    const int gn = n0 + wn + j * 16 + fr;
    const float bv = bias[gn];
#pragma unroll
    for (int i = 0; i < 4; ++i) {
#pragma unroll
      for (int r = 0; r < 4; ++r) {
        const int gm = m0 + wm + i * 16 + fq * 4 + r;
        Y[(long)gm * N + gn] = f2bf(acc[i][j][r] + bv);
      }
    }
  }
}

// ---------------------------------------------------------------- depthwise conv
// out[t,b,c] = sum_k y[t+k-3,b,c] * softmax(weight[h])[k], h = c>>6.
// TWO t's per thread: 8 independent 16B loads cover both 7-tap windows.
__device__ __forceinline__ u32x4 loadY(const unsigned short* Y, int t, long off) {
  if ((unsigned)t < (unsigned)T_DIM)
    return *(const u32x4*)(Y + (long)t * BC + off);
  u32x4 z = {0u, 0u, 0u, 0u};
  return z;
}

__device__ __forceinline__ f32x8 unpack8(u32x4 u) {
  f32x8 r;
#pragma unroll
  for (int i = 0; i < 4; ++i) {
    unsigned w = u[i];
    r[2 * i]     = __uint_as_float(w << 16);
    r[2 * i + 1] = __uint_as_float(w & 0xffff0000u);
  }
  return r;
}

__global__ __launch_bounds__(256, 4) void lconv(
    const unsigned short* __restrict__ Y, const float* __restrict__ W,
    float* __restrict__ O) {
  __shared__ float sm_wf[8 * K_CONV];
  if (threadIdx.x < 8) {
    const int h = threadIdx.x;
    float v[K_CONV];
    float mx = -1e30f;
#pragma unroll
    for (int k = 0; k < K_CONV; ++k) { v[k] = W[h * K_CONV + k]; mx = fmaxf(mx, v[k]); }
    float s = 0.f;
#pragma unroll
    for (int k = 0; k < K_CONV; ++k) { v[k] = __expf(v[k] - mx); s += v[k]; }
    const float inv = 1.f / s;
#pragma unroll
    for (int k = 0; k < K_CONV; ++k) sm_wf[h * K_CONV + k] = v[k] * inv;
  }

  // XCD swizzle: xcd owns t in [xcd*512, xcd*512+512) for each b.
  const int id   = blockIdx.x;            // 0..8191
  const int xcd  = id & 7;
  const int slot = id >> 3;               // 0..1023
  const int b    = slot >> 6;             // 0..15
  const int tl   = slot & 63;             // 0..63
  const int t0   = xcd * 512 + tl * 8 + (threadIdx.x >> 6) * 2;
  const int cvec = threadIdx.x & 63;
  const long off = (long)b * C_DIM + cvec * 8;
  const int h    = cvec >> 3;

  u32x4 v[8];
#pragma unroll
  for (int k = 0; k < 8; ++k) v[k] = loadY(Y, t0 + k - 3, off);

  __syncthreads();
  float wf[K_CONV];
#pragma unroll
  for (int k = 0; k < K_CONV; ++k) wf[k] = sm_wf[h * K_CONV + k];

  f32x8 w0 = unpack8(v[0]);
  f32x8 acc0 = w0 * wf[0];
  f32x8 acc1;
#pragma unroll
  for (int k = 1; k < K_CONV; ++k) {
    f32x8 wk = unpack8(v[k]);
    acc0 += wk * wf[k];
    if (k == 1) acc1 = wk * wf[0];
    else        acc1 += wk * wf[k - 1];
  }
  acc1 += unpack8(v[7]) * wf[6];

  float* op0 = O + (long)t0 * BC + off;
  *(f32x4*)op0       = f32x4{acc0[0], acc0[1], acc0[2], acc0[3]};
  *(f32x4*)(op0 + 4) = f32x4{acc0[4], acc0[5], acc0[6], acc0[7]};
  float* op1 = O + (long)(t0 + 1) * BC + off;
  *(f32x4*)op1       = f32x4{acc1[0], acc1[1], acc1[2], acc1[3]};
  *(f32x4*)(op1 + 4) = f32x4{acc1[4], acc1[5], acc1[6], acc1[7]};
}

// ---------------------------------------------------------------- launch
extern "C" void kernel_launch(void* const* d_in, const int* in_sizes, int n_in,
                              void* d_out, int out_size, void* d_ws, size_t ws_size,
                              hipStream_t stream) {
  const float* x       = (const float*)d_in[0];  // (T,B,C) fp32
  const float* shift_W = (const float*)d_in[1];  // (C,C) fp32
  const float* shift_b = (const float*)d_in[2];  // (C) fp32
  const float* weight  = (const float*)d_in[3];  // (8,7) fp32
  float* out = (float*)d_out;

  unsigned short* Wq = (unsigned short*)d_ws;        // 512 KB bf16 Wq
  unsigned short* Y  = Wq + C_DIM * C_DIM;           // 67 MB bf16 y

  quantize_w<<<(C_DIM * C_DIM) / 256, 256, 0, stream>>>(shift_W, Wq);
  gemm_bt<<<(M_DIM / 128) * (C_DIM / 128), 256, 0, stream>>>(
      x, (const short*)Wq, shift_b, Y);
  lconv<<<(M_DIM / 2) * (C_DIM / 8) / 256, 256, 0, stream>>>(Y, weight, out);
}